// Round 12
// baseline (241.121 us; speedup 1.0000x reference)
//
#include <hip/hip_runtime.h>

// Linear attention, N=8, L=S=8192, H=8, D=Dv=32, fp32.
// out[n,l,h,v] = (sum_d fQ[l,d] * KV[h][d,v]) / (sum_d fQ[l,d]*Ksum[h][d] + eps)
// KV = sum_s fK V^T per (n,h); f(x)=elu(x)+1. /S and *S cancel exactly.
//
// Round-10: occupancy fix. R9 counters: kv Occupancy 9.6% (1 block=4 waves/CU,
// LDS 68.6KB), all pipes <20% -> latency-bound. Halve LDS tiles, double grids:
// kv = 512 blocks x 34.3KB, out = 1024 blocks x 51KB. Keep R9's proven parts:
// contiguous all-head float4 tiles (0 bank conflicts), deterministic partials
// (no atomics), double-buffer + depth-1 register prefetch.

#define RS4 64              // 256 floats per (n,row) = 64 float4
#define EPSV 1e-6f

#define KV_CH 64            // S-chunks (512 blocks -> 2 blocks/CU)
#define KV_ROWS 128         // rows per kv block
#define KV_TILE 8           // rows per iter (LDS 34.3KB)
#define KV_ITERS 16
#define PH4 264             // 1056 floats per (pair,chunk) partial, in float4
#define FIN4 (8 * KV_CH * 8 * PH4)   // float4 offset of final KV (17.3MB partials)

#define KP 67               // kv LDS row pitch (float4); 67%8=3 spreads rows
#define OP 67               // out sQ pitch (float4)
#define KVP 265             // out sKV per-head pitch (float4)

__device__ __forceinline__ float fmap(float x) {
    return x > 0.0f ? x + 1.0f : __expf(x);
}
__device__ __forceinline__ float4 fmap4(float4 v) {
    return make_float4(fmap(v.x), fmap(v.y), fmap(v.z), fmap(v.w));
}
__device__ __forceinline__ float f4c(const float4& v, int i) {
    return i == 0 ? v.x : i == 1 ? v.y : i == 2 ? v.z : v.w;
}

// ---------------------------------------------------------------------------
// Kernel A: block (c, n) accumulates KV[8 heads][32x32] + Ksum over 128 rows.
// 256 threads = 8 head-groups x 32 lanes; lane owns 8d x 4v, sees all rows.
// Double-buffered 8-row LDS tiles (34.3KB), 1 sync/iter, register prefetch.
// ---------------------------------------------------------------------------
__global__ __launch_bounds__(256) void kv_kernel(const float4* __restrict__ Kg,
                                                 const float4* __restrict__ Vg,
                                                 float4* __restrict__ ws)
{
    __shared__ float4 sK[2][KV_TILE * KP];   // 2 x 8.58KB
    __shared__ float4 sV[2][KV_TILE * KP];

    const int n = blockIdx.y, c = blockIdx.x;
    const int t = threadIdx.x;
    const int h = t >> 5;            // head 0..7
    const int q = t & 31;
    const int dq = (q >> 3) * 2;     // d float4 origin: d0 = (q>>3)*8
    const int vs = q & 7;            // v float4 slice

    size_t gbase = ((size_t)n * 8192 + (size_t)c * KV_ROWS) * RS4 + t;

    float acc[8][4];
    float ksum[8];
    #pragma unroll
    for (int a = 0; a < 8; ++a) {
        ksum[a] = 0.0f;
        acc[a][0] = acc[a][1] = acc[a][2] = acc[a][3] = 0.0f;
    }

    float4 pK[2], pV[2];
    #pragma unroll
    for (int k = 0; k < 2; ++k) { pK[k] = Kg[gbase + k * 256]; pV[k] = Vg[gbase + k * 256]; }

    for (int it = 0; it < KV_ITERS; ++it) {
        float4* bK = sK[it & 1];
        float4* bV = sV[it & 1];
        #pragma unroll
        for (int k = 0; k < 2; ++k) {
            const int idx = k * 256 + t;                 // float4 idx in 8-row tile
            const int dst = (idx >> 6) * KP + (idx & 63);
            bK[dst] = fmap4(pK[k]);
            bV[dst] = pV[k];
        }
        if (it + 1 < KV_ITERS) {
            gbase += (size_t)KV_TILE * RS4;              // +512 float4
            #pragma unroll
            for (int k = 0; k < 2; ++k) { pK[k] = Kg[gbase + k * 256]; pV[k] = Vg[gbase + k * 256]; }
        }
        __syncthreads();   // single barrier per iter: buffers alternate
        #pragma unroll
        for (int r = 0; r < KV_TILE; ++r) {
            const float4 k0 = bK[r * KP + h * 8 + dq];
            const float4 k1 = bK[r * KP + h * 8 + dq + 1];
            const float4 v  = bV[r * KP + h * 8 + vs];
            const float kk[8] = {k0.x, k0.y, k0.z, k0.w, k1.x, k1.y, k1.z, k1.w};
            #pragma unroll
            for (int a = 0; a < 8; ++a) {
                ksum[a]   += kk[a];
                acc[a][0] += kk[a] * v.x;
                acc[a][1] += kk[a] * v.y;
                acc[a][2] += kk[a] * v.z;
                acc[a][3] += kk[a] * v.w;
            }
        }
    }

    // deterministic partial store (coalesced float4)
    const size_t pb = ((size_t)(n * KV_CH + c) * 8 + h) * PH4;
    const int d0 = (q >> 3) * 8;
    #pragma unroll
    for (int a = 0; a < 8; ++a)
        ws[pb + (size_t)(d0 + a) * 8 + vs] =
            make_float4(acc[a][0], acc[a][1], acc[a][2], acc[a][3]);
    if (vs == 0) {   // Ksum at float4 idx 256 + d/4
        ws[pb + 256 + dq]     = make_float4(ksum[0], ksum[1], ksum[2], ksum[3]);
        ws[pb + 256 + dq + 1] = make_float4(ksum[4], ksum[5], ksum[6], ksum[7]);
    }
}

// ---------------------------------------------------------------------------
// Reduce: 64 blocks (one per pair), sum 64 chunk-partials -> final region.
// ---------------------------------------------------------------------------
__global__ __launch_bounds__(256) void reduce_kernel(float4* __restrict__ ws)
{
    const int pair = blockIdx.x;          // n*8 + h
    const int n = pair >> 3, h = pair & 7;
    const int t = threadIdx.x;
    const size_t cs = 8 * PH4;            // chunk stride (float4)

    for (int e = t; e < PH4; e += 256) {
        const size_t b = ((size_t)(n * KV_CH) * 8 + h) * PH4 + e;
        float4 s0 = make_float4(0.f, 0.f, 0.f, 0.f), s1 = s0, s2 = s0, s3 = s0;
        #pragma unroll
        for (int c = 0; c < KV_CH; c += 4) {
            const float4 a0 = ws[b + (size_t)(c + 0) * cs];
            const float4 a1 = ws[b + (size_t)(c + 1) * cs];
            const float4 a2 = ws[b + (size_t)(c + 2) * cs];
            const float4 a3 = ws[b + (size_t)(c + 3) * cs];
            s0.x += a0.x; s0.y += a0.y; s0.z += a0.z; s0.w += a0.w;
            s1.x += a1.x; s1.y += a1.y; s1.z += a1.z; s1.w += a1.w;
            s2.x += a2.x; s2.y += a2.y; s2.z += a2.z; s2.w += a2.w;
            s3.x += a3.x; s3.y += a3.y; s3.z += a3.z; s3.w += a3.w;
        }
        ws[FIN4 + (size_t)pair * PH4 + e] =
            make_float4(s0.x + s1.x + s2.x + s3.x, s0.y + s1.y + s2.y + s3.y,
                        s0.z + s1.z + s2.z + s3.z, s0.w + s1.w + s2.w + s3.w);
    }
}

// ---------------------------------------------------------------------------
// Kernel B: block (cL, n): 64 rows x all 8 heads, 4 iters of 16-row Q tiles.
// LDS = sKV 33.9KB + sQ 17.2KB = 51KB -> 3 blocks/CU; grid 1024.
// Lane = 4 rows x 4 v for its head. All global accesses lane-consecutive.
// ---------------------------------------------------------------------------
#define BROWS 64

__global__ __launch_bounds__(256) void out_kernel(const float4* __restrict__ Q,
                                                  const float4* __restrict__ ws,
                                                  float4* __restrict__ out)
{
    __shared__ float4 sKV[8 * KVP];      // 33.9KB
    __shared__ float4 sQ[16 * OP];       // 17.2KB

    const int n = blockIdx.y, cL = blockIdx.x;
    const int t = threadIdx.x;
    const int h = t >> 5;
    const int q = t & 31;
    const int rblk = q >> 3;             // 0..3 ; lane rows = rblk + 4j
    const int vs = q & 7;                // v float4 slice

    size_t gbase = ((size_t)n * 8192 + (size_t)cL * BROWS) * RS4 + t;

    // prefetch Q tile 0 (16 rows = 1024 float4, 4 per thread)
    float4 pf[4];
    #pragma unroll
    for (int k = 0; k < 4; ++k) pf[k] = Q[gbase + k * 256];

    // load final KV (8 heads x 1056 floats) into LDS
    {
        const size_t fb = FIN4 + (size_t)n * 8 * PH4;
        #pragma unroll
        for (int k = 0; k < 9; ++k) {
            const int p = k * 256 + t;
            if (p < 8 * PH4) {
                const int hh = p / PH4, e = p - hh * PH4;
                sKV[hh * KVP + e] = ws[fb + p];
            }
        }
    }

    for (int it = 0; it < 4; ++it) {
        __syncthreads();     // previous compute done -> safe to overwrite sQ
        #pragma unroll
        for (int k = 0; k < 4; ++k) {
            const int idx = k * 256 + t;                  // float4 idx in 16-row tile
            sQ[(idx >> 6) * OP + (idx & 63)] = fmap4(pf[k]);
        }
        if (it + 1 < 4) {
            gbase += (size_t)16 * RS4;                    // +1024 float4
            #pragma unroll
            for (int k = 0; k < 4; ++k) pf[k] = Q[gbase + k * 256];
        }
        __syncthreads();     // sQ (and, at it=0, sKV) visible

        float acc[4][4];
        float den[4];
        #pragma unroll
        for (int j = 0; j < 4; ++j) {
            den[j] = 0.0f;
            acc[j][0] = acc[j][1] = acc[j][2] = acc[j][3] = 0.0f;
        }

        #pragma unroll
        for (int dc = 0; dc < 8; ++dc) {
            const float4 ks = sKV[h * KVP + 256 + dc];
            float4 qr[4];
            #pragma unroll
            for (int j = 0; j < 4; ++j)
                qr[j] = sQ[(rblk + 4 * j) * OP + h * 8 + dc];
            #pragma unroll
            for (int dd = 0; dd < 4; ++dd) {
                const float4 kv = sKV[h * KVP + (dc * 4 + dd) * 8 + vs];
                const float ksd = f4c(ks, dd);
                #pragma unroll
                for (int j = 0; j < 4; ++j) {
                    const float qv = f4c(qr[j], dd);
                    acc[j][0] += qv * kv.x;
                    acc[j][1] += qv * kv.y;
                    acc[j][2] += qv * kv.z;
                    acc[j][3] += qv * kv.w;
                    den[j]    += qv * ksd;
                }
            }
        }

        const size_t ob = ((size_t)n * 8192 + (size_t)cL * BROWS + it * 16 + rblk) * RS4
                        + h * 8 + vs;
        #pragma unroll
        for (int j = 0; j < 4; ++j) {
            const float z = 1.0f / (den[j] + EPSV);
            out[ob + (size_t)(4 * j) * RS4] =
                make_float4(acc[j][0] * z, acc[j][1] * z, acc[j][2] * z, acc[j][3] * z);
        }
    }
}

extern "C" void kernel_launch(void* const* d_in, const int* in_sizes, int n_in,
                              void* d_out, int out_size, void* d_ws, size_t ws_size,
                              hipStream_t stream)
{
    const float4* Q = (const float4*)d_in[0];
    const float4* K = (const float4*)d_in[1];
    const float4* V = (const float4*)d_in[2];
    float4* outp = (float4*)d_out;
    float4* ws = (float4*)d_ws;

    // no memset needed: partials + final are fully overwritten each launch

    dim3 gA(KV_CH, 8);
    kv_kernel<<<gA, 256, 0, stream>>>(K, V, ws);

    reduce_kernel<<<64, 256, 0, stream>>>(ws);

    dim3 gB(8192 / BROWS, 8);
    out_kernel<<<gB, 256, 0, stream>>>(Q, ws, outp);
}